// Round 11
// baseline (232.226 us; speedup 1.0000x reference)
//
#include <hip/hip_runtime.h>
#include <hip/hip_bf16.h>

#define NHEAD 12
#define BATCH 8
#define SEQ 1024
#define LOG2E 1.4426950408889634f

typedef __bf16 bf16x8 __attribute__((ext_vector_type(8)));
typedef float  f32x4  __attribute__((ext_vector_type(4)));

// global_load_lds completion is vmcnt-tracked; with distinct __shared__
// symbols the compiler emits no waits itself (R8 race) -> explicit waits.
#define WAITVM0 asm volatile("s_waitcnt vmcnt(0)" ::: "memory")
// proj: keep the newest stage (4 loads) in flight across the barrier
#define WAITVM4 asm volatile("s_waitcnt vmcnt(4)" ::: "memory")
// attn: leave the newest V-load in flight across the barrier
#define WAITVM1 asm volatile("s_waitcnt vmcnt(1)" ::: "memory")

#define MFMA(A, B, C) __builtin_amdgcn_mfma_f32_16x16x32_bf16(A, B, C, 0, 0, 0)

__device__ __forceinline__ unsigned short f2bf(float f) {
    union { float f; unsigned u; } v; v.f = f;
    unsigned u = v.u;
    u += 0x7fff + ((u >> 16) & 1);   // RNE
    return (unsigned short)(u >> 16);
}

__device__ __forceinline__ unsigned pkbf(float a, float b) {
    union { __hip_bfloat162 h; unsigned u; } cv;
    cv.h = __float22bfloat162_rn(make_float2(a, b));   // RNE, packed cvt; a->lo16, b->hi16
    return cv.u;
}

__device__ __forceinline__ void gload_lds16(const void* g, void* l) {
    __builtin_amdgcn_global_load_lds(
        (const __attribute__((address_space(1))) unsigned*)g,
        (__attribute__((address_space(3))) unsigned*)l, 16, 0, 0);
}

// region sizes (floats)
#define SZ_X    6291456
#define SZ_QKVW 1769472
#define SZ_PW   589824
#define CONV_TOTAL 15532032   // x + pos + qkv_w + pq_w + pk_w

// ---------------------------------------------------------------------------
// Kernel 0: convert fp32 inputs/weights -> bf16 in workspace (once).
// ---------------------------------------------------------------------------
__global__ __launch_bounds__(256) void convert_kernel(
    const float* __restrict__ x, const float* __restrict__ pos,
    const float* __restrict__ qkv_w, const float* __restrict__ pq_w,
    const float* __restrict__ pk_w, unsigned short* __restrict__ dst)
{
    const size_t i4 = ((size_t)blockIdx.x * 256 + threadIdx.x) * 4;
    if (i4 >= CONV_TOTAL) return;
    const float* src; size_t off;
    if (i4 < SZ_X)                { src = x;     off = i4; }
    else if (i4 < 2 * SZ_X)       { src = pos;   off = i4 - SZ_X; }
    else if (i4 < 2 * SZ_X + SZ_QKVW) { src = qkv_w; off = i4 - 2 * SZ_X; }
    else if (i4 < 2 * SZ_X + SZ_QKVW + SZ_PW) { src = pq_w; off = i4 - 2 * SZ_X - SZ_QKVW; }
    else                          { src = pk_w;  off = i4 - 2 * SZ_X - SZ_QKVW - SZ_PW; }
    float4 v = *(const float4*)(src + off);
    ushort4 o;
    o.x = f2bf(v.x); o.y = f2bf(v.y); o.z = f2bf(v.z); o.w = f2bf(v.w);
    *(ushort4*)(dst + i4) = o;
}

// ---------------------------------------------------------------------------
// Kernel 1: fused projection GEMM.
// R20 vs R19 (82.4 us steady; WRITE still 83 MB = ~20 MB scratch spill at
// VGPR=84): the allocator targeted 6 waves/SIMD occupancy that the 48 KB
// LDS (3 blocks/CU = 3 waves/SIMD) makes impossible, spilling acc+q2s.
// ONE change: amdgpu_waves_per_eu(3,3) aligns the allocator's occupancy
// target with the LDS ceiling -> it may use up to ~168 VGPRs, keeping the
// gg2 dual-output state (accK 64 + q2s 32) fully in registers.
// ---------------------------------------------------------------------------

#define PROJ_STAGE(K0, AS, BS) do {                                          \
    const int k0_ = (K0);                                                    \
    const unsigned short* asrc_; int acol_;                                  \
    if (gg == 3)                    { asrc_ = posb; acol_ = k0_; }           \
    else if (gg == 2 && k0_ >= 768) { asrc_ = posb; acol_ = k0_ - 768; }     \
    else                            { asrc_ = xb;   acol_ = k0_; }           \
    gload_lds16(asrc_ + (size_t)(m0 + r0) * 768 + acol_ + q0 * 8, &AS[base0]);\
    gload_lds16(asrc_ + (size_t)(m0 + r1) * 768 + acol_ + q1 * 8, &AS[base1]);\
    const unsigned short* wsrc_; int wro_, wco_;                             \
    if (gg == 0)      { wsrc_ = qkvw; wro_ = colbase;        wco_ = k0_; }   \
    else if (gg == 1) { wsrc_ = qkvw; wro_ = 1536 + colbase; wco_ = k0_; }   \
    else if (gg == 2) {                                                      \
        if (k0_ < 768) { wsrc_ = qkvw; wro_ = 768 + colbase; wco_ = k0_; }   \
        else           { wsrc_ = pqw;  wro_ = colbase;       wco_ = k0_ - 768; }\
    } else            { wsrc_ = pkw;  wro_ = colbase;        wco_ = k0_; }   \
    gload_lds16(wsrc_ + (size_t)(wro_ + r0) * 768 + wco_ + q0 * 8, &BS[base0]);\
    gload_lds16(wsrc_ + (size_t)(wro_ + r1) * 768 + wco_ + q1 * 8, &BS[base1]);\
} while (0)

#define PROJ_COMPUTE(AS, BS, ACC) do {                                       \
    bf16x8 af[4], bfr[4];                                                    \
    _Pragma("unroll")                                                        \
    for (int mt = 0; mt < 4; ++mt) {                                         \
        const int rr = wm + mt * 16 + col16;                                 \
        af[mt] = *(const bf16x8*)&AS[rr * 32 + ((quad ^ ((rr >> 1) & 3)) * 8)];\
    }                                                                        \
    _Pragma("unroll")                                                        \
    for (int nt = 0; nt < 4; ++nt) {                                         \
        const int rr = wn + nt * 16 + col16;                                 \
        bfr[nt] = *(const bf16x8*)&BS[rr * 32 + ((quad ^ ((rr >> 1) & 3)) * 8)];\
    }                                                                        \
    _Pragma("unroll")                                                        \
    for (int mt = 0; mt < 4; ++mt)                                           \
        _Pragma("unroll")                                                    \
        for (int nt = 0; nt < 4; ++nt)                                       \
            ACC[mt][nt] = MFMA(af[mt], bfr[nt], ACC[mt][nt]);                \
} while (0)

// one 3-phase trip of the ring; staging guards use nk (global K extent)
#define PROJ_TRIP(KT, ACC) do {                                              \
    const int kt_ = (KT);                                                    \
    WAITVM4;                                                                 \
    __syncthreads();                                                         \
    PROJ_STAGE((kt_ + 2) * 32, As2, Bs2);                                    \
    PROJ_COMPUTE(As0, Bs0, ACC);                                             \
    WAITVM4;                                                                 \
    __syncthreads();                                                         \
    if (kt_ + 3 < nk) PROJ_STAGE((kt_ + 3) * 32, As0, Bs0);                  \
    PROJ_COMPUTE(As1, Bs1, ACC);                                             \
    if (kt_ + 3 >= nk) { WAITVM0; } else { WAITVM4; }                        \
    __syncthreads();                                                         \
    if (kt_ + 4 < nk) PROJ_STAGE((kt_ + 4) * 32, As1, Bs1);                  \
    PROJ_COMPUTE(As2, Bs2, ACC);                                             \
} while (0)

// LDS-staged epilogue: 4 passes of 32 rows through As0 (used [32][128]).
// SRCEXPR is an f32 expression in mt,nt,r; BADDEXPR may use c (col in [0,768));
// DSTEXPR may use b,l,h,dd (dd multiple of 8 -> 16B-aligned store).
#define PROJ_EPI(SRCEXPR, BADDEXPR, BMULV, DSTEXPR) do {                     \
    _Pragma("unroll")                                                        \
    for (int p = 0; p < 4; ++p) {                                            \
        __syncthreads();                                                     \
        if ((wm >> 6) == (p >> 1)) {                                         \
            _Pragma("unroll")                                                \
            for (int mth = 0; mth < 2; ++mth) {                              \
                const int mt = ((p & 1) << 1) | mth;                         \
                _Pragma("unroll")                                            \
                for (int nt = 0; nt < 4; ++nt) {                             \
                    const int c = colbase + wn + nt * 16 + col16;            \
                    const float badd = (BADDEXPR);                           \
                    const int lrb  = mth * 16 + quad * 4;                    \
                    const int ccol = wn + nt * 16 + col16;                   \
                    _Pragma("unroll")                                        \
                    for (int r = 0; r < 4; ++r)                              \
                        As0[(lrb + r) * 128 + ccol] =                        \
                            f2bf(((SRCEXPR) + badd) * (BMULV));              \
                }                                                            \
            }                                                                \
        }                                                                    \
        __syncthreads();                                                     \
        _Pragma("unroll")                                                    \
        for (int j = 0; j < 2; ++j) {                                        \
            const int u = tid + 256 * j;                                     \
            const int rowp = u >> 4;          /* 0..31 */                    \
            const int seg  = u & 15;          /* 8 shorts each */            \
            const int m = m0 + p * 32 + rowp;                                \
            const int b = m >> 10, l = m & 1023;                             \
            const int c = colbase + seg * 8;                                 \
            const int h = c >> 6, dd = c & 63;                               \
            uint4 v = *(const uint4*)&As0[rowp * 128 + seg * 8];             \
            *(uint4*)(DSTEXPR) = v;                                          \
        }                                                                    \
    }                                                                        \
} while (0)

// RAW variant: SHORTEXPR yields an unsigned short for (mt,nt,r) — already bf16.
#define PROJ_EPI_RAW(SHORTEXPR, DSTEXPR) do {                                \
    _Pragma("unroll")                                                        \
    for (int p = 0; p < 4; ++p) {                                            \
        __syncthreads();                                                     \
        if ((wm >> 6) == (p >> 1)) {                                         \
            _Pragma("unroll")                                                \
            for (int mth = 0; mth < 2; ++mth) {                              \
                const int mt = ((p & 1) << 1) | mth;                         \
                _Pragma("unroll")                                            \
                for (int nt = 0; nt < 4; ++nt) {                             \
                    const int lrb  = mth * 16 + quad * 4;                    \
                    const int ccol = wn + nt * 16 + col16;                   \
                    _Pragma("unroll")                                        \
                    for (int r = 0; r < 4; ++r)                              \
                        As0[(lrb + r) * 128 + ccol] = (SHORTEXPR);           \
                }                                                            \
            }                                                                \
        }                                                                    \
        __syncthreads();                                                     \
        _Pragma("unroll")                                                    \
        for (int j = 0; j < 2; ++j) {                                        \
            const int u = tid + 256 * j;                                     \
            const int rowp = u >> 4;          /* 0..31 */                    \
            const int seg  = u & 15;          /* 8 shorts each */            \
            const int m = m0 + p * 32 + rowp;                                \
            const int b = m >> 10, l = m & 1023;                             \
            const int c = colbase + seg * 8;                                 \
            const int h = c >> 6, dd = c & 63;                               \
            uint4 v = *(const uint4*)&As0[rowp * 128 + seg * 8];             \
            *(uint4*)(DSTEXPR) = v;                                          \
        }                                                                    \
    }                                                                        \
} while (0)

__global__ __launch_bounds__(256, 3)
__attribute__((amdgpu_waves_per_eu(3, 3)))
void proj_kernel(
    const unsigned short* __restrict__ xb, const unsigned short* __restrict__ posb,
    const unsigned short* __restrict__ qkvw, const unsigned short* __restrict__ pqw,
    const unsigned short* __restrict__ pkw,
    const float* __restrict__ qkv_b, const float* __restrict__ pq_b,
    const float* __restrict__ pk_b,
    unsigned short* __restrict__ Q2, unsigned short* __restrict__ K2,
    unsigned short* __restrict__ Vt, int band)
{
    __shared__ unsigned short As0[128 * 32];
    __shared__ unsigned short As1[128 * 32];
    __shared__ unsigned short As2[128 * 32];
    __shared__ unsigned short Bs0[128 * 32];
    __shared__ unsigned short Bs1[128 * 32];
    __shared__ unsigned short Bs2[128 * 32];

    const int id  = blockIdx.x;
    const int xcd = id & 7;
    const int idx = id >> 3;
    const int t24 = (idx / band + 12) % 24;         // gg2 (dual-K) tiles first
    const int m0 = (xcd * band + idx % band) * 128;
    const int gg = t24 / 6;
    const int colbase = (t24 % 6) * 128;            // column within the group
    const int nk = (gg == 2) ? 48 : 24;             // multiple of 3

    const int tid   = threadIdx.x;
    const int lane  = tid & 63;
    const int w     = tid >> 6;
    const int wm    = (w & 1) * 64;
    const int wn    = (w >> 1) * 64;
    const int quad  = lane >> 4;
    const int col16 = lane & 15;

    const int c0 = w * 64 + lane;
    const int c1 = c0 + 256;
    const int r0 = c0 >> 2, q0 = (c0 & 3) ^ ((c0 >> 3) & 3);
    const int r1 = c1 >> 2, q1 = (c1 & 3) ^ ((c1 >> 3) & 3);
    const int base0 = (w * 64) * 8;
    const int base1 = (w * 64 + 256) * 8;

    f32x4 accK[4][4];
    const f32x4 fzero = {0.f, 0.f, 0.f, 0.f};
#pragma unroll
    for (int mt = 0; mt < 4; ++mt)
#pragma unroll
        for (int nt = 0; nt < 4; ++nt) accK[mt][nt] = fzero;

    // 3-ring prologue: two stages in flight
    PROJ_STAGE(0, As0, Bs0);
    PROJ_STAGE(32, As1, Bs1);

    if (gg == 2) {
        // phases 0-23: x·Wk -> accK
        for (int kt = 0; kt < 24; kt += 3) PROJ_TRIP(kt, accK);

        // SNAPSHOT: pack Q2k bf16 (exact old-g1 arithmetic) into 32 u32 regs.
        // The 4 bias loads force one compiler drain here — one-time cost.
        uint2 q2s[4][4];
#pragma unroll
        for (int nt = 0; nt < 4; ++nt) {
            const int c = colbase + wn + nt * 16 + col16;
            const float bias = qkv_b[768 + c];
#pragma unroll
            for (int mt = 0; mt < 4; ++mt) {
                q2s[mt][nt].x = pkbf((accK[mt][nt][0] + bias) * (LOG2E / 48.0f),
                                     (accK[mt][nt][1] + bias) * (LOG2E / 48.0f));
                q2s[mt][nt].y = pkbf((accK[mt][nt][2] + bias) * (LOG2E / 48.0f),
                                     (accK[mt][nt][3] + bias) * (LOG2E / 48.0f));
            }
        }

        // phases 24-47: += pos·Wpq (same acc — R7 g3 accumulation order)
        for (int kt = 24; kt < 48; kt += 3) PROJ_TRIP(kt, accK);

        // Q2[64:128] from the packed snapshot (already bf16)
        PROJ_EPI_RAW(
            (unsigned short)((r & 2) ? ((r & 1) ? (q2s[mt][nt].y >> 16)
                                                : (q2s[mt][nt].y & 0xffffu))
                                     : ((r & 1) ? (q2s[mt][nt].x >> 16)
                                                : (q2s[mt][nt].x & 0xffffu))),
            &Q2[((size_t)(b * NHEAD + h) * 1024 + l) * 128 + 64 + dd]);
        // K2[0:64] = x·Wk + pos·Wpq + bk + bpq
        PROJ_EPI(accK[mt][nt][r], qkv_b[768 + c] + pq_b[c], 1.0f,
                 &K2[((size_t)(b * NHEAD + h) * 1024 + l) * 128 + dd]);
        return;
    }

    for (int kt = 0; kt < 24; kt += 3) PROJ_TRIP(kt, accK);

    if (gg == 1) {
        // V: 8B uint2 direct path (6/24 tiles only)
#pragma unroll
        for (int mt = 0; mt < 4; ++mt) {
            const int mbase = m0 + wm + mt * 16 + quad * 4;
#pragma unroll
            for (int nt = 0; nt < 4; ++nt) {
                const int c = colbase + wn + nt * 16 + col16;
                const int b = mbase >> 10, l0 = mbase & 1023;
                const int h = c >> 6, dd = c & 63;
                const float bias = qkv_b[1536 + c];
                uint2 pk;
                pk.x = pkbf(accK[mt][nt][0] + bias, accK[mt][nt][1] + bias);
                pk.y = pkbf(accK[mt][nt][2] + bias, accK[mt][nt][3] + bias);
                *(uint2*)&Vt[((size_t)(b * NHEAD + h) * 64 + dd) * 1024 + l0] = pk;
            }
        }
    } else if (gg == 0) {
        PROJ_EPI(accK[mt][nt][r], qkv_b[c], LOG2E,
                 &Q2[((size_t)(b * NHEAD + h) * 1024 + l) * 128 + dd]);
    } else {
        PROJ_EPI(accK[mt][nt][r], pk_b[c], 1.0f,
                 &K2[((size_t)(b * NHEAD + h) * 1024 + l) * 128 + 64 + dd]);
    }
}

// ---------------------------------------------------------------------------
// Kernel 2: flash attention with LAG-1 PV pipelining + counted vmcnt (R16).
// ---------------------------------------------------------------------------

#define ATTN_STG(J0, KS, VS) do {                                            \
    const int j0_ = (J0);                                                    \
    gload_lds16(&K2[q2base + (size_t)(j0_ + kr0) * 128 + kc0 * 8], &KS[kbase0]);\
    gload_lds16(&K2[q2base + (size_t)(j0_ + kr1) * 128 + kc1 * 8], &KS[kbase1]);\
    gload_lds16(&Vt[vtbase + (size_t)vr * 1024 + j0_ + vc * 8],    &VS[vbase]);\
} while (0)

#define ATTN_PV(VS, PSR) do {                                                \
    bf16x8 bp0 = *(const bf16x8*)&PSR[w][col16][quad * 8];                   \
    bf16x8 bp1 = *(const bf16x8*)&PSR[w][16 + col16][quad * 8];              \
    _Pragma("unroll")                                                        \
    for (int c2 = 0; c2 < 4; ++c2) {                                         \
        const int rv = c2 * 16 + col16;                                      \
        bf16x8 av = *(const bf16x8*)&VS[rv * 32 + ((quad ^ ((rv >> 2) & 3)) * 8)];\
        o[0][c2] = MFMA(av, bp0, o[0][c2]);                                  \
        o[1][c2] = MFMA(av, bp1, o[1][c2]);                                  \
    }                                                                        \
} while (0)

#define ATTN_QK(KS, PSW) do {                                                \
    f32x4 st[2][2] = {{fzero, fzero}, {fzero, fzero}};                       \
    _Pragma("unroll")                                                        \
    for (int kk = 0; kk < 4; ++kk) {                                         \
        const int rrj0 = col16, rrj1 = 16 + col16;                           \
        bf16x8 kf0 = *(const bf16x8*)&KS[rrj0 * 128 + (((kk * 4 + quad) ^ (rrj0 & 15)) * 8)];\
        bf16x8 kf1 = *(const bf16x8*)&KS[rrj1 * 128 + (((kk * 4 + quad) ^ (rrj1 & 15)) * 8)];\
        _Pragma("unroll")                                                    \
        for (int qt = 0; qt < 2; ++qt) {                                     \
            st[0][qt] = MFMA(kf0, bq[qt][kk], st[0][qt]);                    \
            st[1][qt] = MFMA(kf1, bq[qt][kk], st[1][qt]);                    \
        }                                                                    \
    }                                                                        \
    _Pragma("unroll")                                                        \
    for (int qt = 0; qt < 2; ++qt) {                                         \
        float p0[4], p1[4], s = 0.f;                                         \
        _Pragma("unroll")                                                    \
        for (int r = 0; r < 4; ++r) {                                        \
            p0[r] = __builtin_amdgcn_exp2f(st[0][qt][r]);                    \
            p1[r] = __builtin_amdgcn_exp2f(st[1][qt][r]);                    \
            s += p0[r] + p1[r];                                              \
        }                                                                    \
        lsum[qt] += s;                                                       \
        uint2 w0, w1;                                                        \
        w0.x = pkbf(p0[0], p0[1]); w0.y = pkbf(p0[2], p0[3]);                \
        w1.x = pkbf(p1[0], p1[1]); w1.y = pkbf(p1[2], p1[3]);                \
        *(uint2*)&PSW[w][qt * 16 + col16][quad * 4]      = w0;               \
        *(uint2*)&PSW[w][qt * 16 + col16][16 + quad * 4] = w1;               \
    }                                                                        \
} while (0)

// phase: DOPV/DOST are compile-time 0/1
#define ATTN_PHASE(J, KQK, KST, VPV, VST, PSW, PSR, DOPV, DOST) do {         \
    WAITVM1;                                                                 \
    __syncthreads();                                                         \
    if (DOST) ATTN_STG(((J) + 1) * 32, KST, VST);                            \
    if (DOPV) ATTN_PV(VPV, PSR);                                             \
    ATTN_QK(KQK, PSW);                                                       \
} while (0)

__global__ __launch_bounds__(256, 3) void attn_kernel(
    const unsigned short* __restrict__ Q2, const unsigned short* __restrict__ K2,
    const unsigned short* __restrict__ Vt, float* __restrict__ out, int b0)
{
    __shared__ unsigned short K2sA[32 * 128];
    __shared__ unsigned short K2sB[32 * 128];
    __shared__ unsigned short VtX[64 * 32];
    __shared__ unsigned short VtY[64 * 32];
    __shared__ unsigned short VtZ[64 * 32];
    __shared__ unsigned short Ps0[4][32][40];
    __shared__ unsigned short Ps1[4][32][40];

    const int bh_l = blockIdx.x;
    const int b = b0 + bh_l / NHEAD, h = bh_l % NHEAD;
    const int tid   = threadIdx.x;
    const int lane  = tid & 63;
    const int w     = tid >> 6;
    const int quad  = lane >> 4;
    const int col16 = lane & 15;
    const int qbase = blockIdx.y * 128 + w * 32;

    const size_t q2base = (size_t)bh_l * 1024 * 128;
    const size_t vtbase = (size_t)bh_l * 64 * 1024;

    const int kL0 = w * 64 + lane, kL1 = kL0 + 256;
    const int kr0 = kL0 >> 4, kc0 = (kL0 & 15) ^ (kr0 & 15);
    const int kr1 = kL1 >> 4, kc1 = (kL1 & 15) ^ (kr1 & 15);
    const int vL  = w * 64 + lane;
    const int vr  = vL >> 2,  vc  = (vL & 3) ^ ((vL >> 4) & 3);
    const int kbase0 = (w * 64) * 8, kbase1 = (w * 64 + 256) * 8;
    const int vbase  = (w * 64) * 8;

    bf16x8 bq[2][4];
#pragma unroll
    for (int qt = 0; qt < 2; ++qt)
#pragma unroll
        for (int kk = 0; kk < 4; ++kk)
            bq[qt][kk] = *(const bf16x8*)&Q2[q2base +
                (size_t)(qbase + qt * 16 + col16) * 128 + kk * 32 + quad * 8];

    f32x4 o[2][4];
    const f32x4 fzero = {0.f, 0.f, 0.f, 0.f};
#pragma unroll
    for (int qt = 0; qt < 2; ++qt)
#pragma unroll
        for (int c2 = 0; c2 < 4; ++c2) o[qt][c2] = fzero;
    float lsum[2] = {0.f, 0.f};

    // prologue: stage 0 -> (K2sA, VtX)
    ATTN_STG(0, K2sA, VtX);

    // phase 0 (pattern J%6==0, no PV): stage 1 -> (K2sB, VtY); QK A -> Ps0
    ATTN_PHASE(0, K2sA, K2sB, VtZ, VtY, Ps0, Ps1, 0, 1);

    // phases 1..30 in 5 trips of 6 (patterns J%6 = 1,2,3,4,5,0)
    for (int j = 1; j < 31; j += 6) {
        ATTN_PHASE(j + 0, K2sB, K2sA, VtX, VtZ, Ps1, Ps0, 1, 1);
        ATTN_PHASE(j + 1, K2sA, K2sB, VtY, VtX, Ps0, Ps1, 1, 1);
        ATTN_PHASE(j + 2, K2sB, K2sA, VtZ, VtY, Ps1, Ps0, 1, 1);
        ATTN_PHASE(j + 3, K2sA, K2sB, VtX, VtZ, Ps0, Ps1, 1, 1);
        ATTN_PHASE(j + 4, K2sB, K2sA, VtY, VtX, Ps1, Ps0, 1, 1);
        ATTN_PHASE(j + 5, K2sA, K2sB, VtZ, VtY, Ps0, Ps1, 1, 1);
    }

    // phase 31 (pattern J%6==1, no stage): PV_30 (VtX, Ps0); QK B -> Ps1
    ATTN_PHASE(31, K2sB, K2sA, VtX, VtZ, Ps1, Ps0, 1, 0);

    // final PV_31: V31 (VtY) was left in flight by phase 31's vmcnt(1)
    // -> drain own DMA, then barrier so all waves' quarters are complete.
    WAITVM0;
    __syncthreads();
    ATTN_PV(VtY, Ps1);

    // ---- final denominator: reduce partials across the 4 sixteens
#pragma unroll
    for (int qt = 0; qt < 2; ++qt) {
        lsum[qt] += __shfl_xor(lsum[qt], 16, 64);
        lsum[qt] += __shfl_xor(lsum[qt], 32, 64);
    }

    // ---- epilogue: o[qt][c2][r] = O^T[d = c2*16+quad*4+r][q]
#pragma unroll
    for (int qt = 0; qt < 2; ++qt) {
        const float inv = 1.0f / lsum[qt];
        const int q = qbase + qt * 16 + col16;
#pragma unroll
        for (int c2 = 0; c2 < 4; ++c2) {
#pragma unroll
            for (int r = 0; r < 4; ++r) {
                const int dd = c2 * 16 + quad * 4 + r;
                out[(((size_t)(b * 1024 + q)) * 12 + h) * 64 + dd] = o[qt][c2][r] * inv;
            }
        }
    }
}

extern "C" void kernel_launch(void* const* d_in, const int* in_sizes, int n_in,
                              void* d_out, int out_size, void* d_ws, size_t ws_size,
                              hipStream_t stream) {
    const float* x     = (const float*)d_in[0];
    const float* pos   = (const float*)d_in[1];
    const float* qkv_w = (const float*)d_in[2];
    const float* qkv_b = (const float*)d_in[3];
    const float* pq_w  = (const float*)d_in[4];
    const float* pq_b  = (const float*)d_in[5];
    const float* pk_w  = (const float*)d_in[6];
    const float* pk_b  = (const float*)d_in[7];
    float* out = (float*)d_out;

    // ws layout (shorts): [xb | posb | qkvw | pqw | pkw | Q2 | K2 | Vt]
    unsigned short* ws   = (unsigned short*)d_ws;
    unsigned short* xb   = ws;
    unsigned short* posb = xb + SZ_X;
    unsigned short* qkvw = posb + SZ_X;
    unsigned short* pqw  = qkvw + SZ_QKVW;
    unsigned short* pkw  = pqw + SZ_PW;
    unsigned short* cbuf = pkw + SZ_PW;              // = ws + CONV_TOTAL

    const size_t conv_bytes = (size_t)CONV_TOTAL * 2;
    const size_t per_batch  = (size_t)NHEAD * 1024 * 128 * 4
                            + (size_t)NHEAD * 64 * 1024 * 2;   // 7,864,320 B
    int cb = BATCH;
    while (cb > 1 && conv_bytes + (size_t)cb * per_batch > ws_size) cb >>= 1;

    unsigned short* Q2 = cbuf;
    unsigned short* K2 = Q2 + (size_t)cb * NHEAD * 1024 * 128;
    unsigned short* Vt = K2 + (size_t)cb * NHEAD * 1024 * 128;

    convert_kernel<<<(CONV_TOTAL / 4 + 255) / 256, 256, 0, stream>>>(
        x, pos, qkv_w, pq_w, pk_w, ws);

    for (int b0 = 0; b0 < BATCH; b0 += cb) {
        proj_kernel<<<dim3(cb * 192), 256, 0, stream>>>(
            xb + (size_t)b0 * 1024 * 768, posb + (size_t)b0 * 1024 * 768,
            qkvw, pqw, pkw, qkv_b, pq_b, pk_b, Q2, K2, Vt, cb);
        attn_kernel<<<dim3(cb * NHEAD, 8), 256, 0, stream>>>(Q2, K2, Vt, out, b0);
    }
}

// Round 12
// 219.834 us; speedup vs baseline: 1.0564x; 1.0564x over previous
//
#include <hip/hip_runtime.h>
#include <hip/hip_bf16.h>

#define NHEAD 12
#define BATCH 8
#define SEQ 1024
#define LOG2E 1.4426950408889634f

typedef __bf16 bf16x8 __attribute__((ext_vector_type(8)));
typedef float  f32x4  __attribute__((ext_vector_type(4)));

// global_load_lds completion is vmcnt-tracked; with distinct __shared__
// symbols the compiler emits no waits itself (R8 race) -> explicit waits.
#define WAITVM0 asm volatile("s_waitcnt vmcnt(0)" ::: "memory")
// proj: keep the newest stage (4 loads) in flight across the barrier
#define WAITVM4 asm volatile("s_waitcnt vmcnt(4)" ::: "memory")
// attn: leave the newest V-load in flight across the barrier
#define WAITVM1 asm volatile("s_waitcnt vmcnt(1)" ::: "memory")

#define MFMA(A, B, C) __builtin_amdgcn_mfma_f32_16x16x32_bf16(A, B, C, 0, 0, 0)

__device__ __forceinline__ unsigned short f2bf(float f) {
    union { float f; unsigned u; } v; v.f = f;
    unsigned u = v.u;
    u += 0x7fff + ((u >> 16) & 1);   // RNE
    return (unsigned short)(u >> 16);
}

__device__ __forceinline__ unsigned pkbf(float a, float b) {
    union { __hip_bfloat162 h; unsigned u; } cv;
    cv.h = __float22bfloat162_rn(make_float2(a, b));   // RNE, packed cvt; a->lo16, b->hi16
    return cv.u;
}

__device__ __forceinline__ void gload_lds16(const void* g, void* l) {
    __builtin_amdgcn_global_load_lds(
        (const __attribute__((address_space(1))) unsigned*)g,
        (__attribute__((address_space(3))) unsigned*)l, 16, 0, 0);
}

// region sizes (floats)
#define SZ_X    6291456
#define SZ_QKVW 1769472
#define SZ_PW   589824
#define CONV_TOTAL 15532032   // x + pos + qkv_w + pq_w + pk_w

// ---------------------------------------------------------------------------
// Kernel 0: convert fp32 inputs/weights -> bf16 in workspace (once).
// ---------------------------------------------------------------------------
__global__ __launch_bounds__(256) void convert_kernel(
    const float* __restrict__ x, const float* __restrict__ pos,
    const float* __restrict__ qkv_w, const float* __restrict__ pq_w,
    const float* __restrict__ pk_w, unsigned short* __restrict__ dst)
{
    const size_t i4 = ((size_t)blockIdx.x * 256 + threadIdx.x) * 4;
    if (i4 >= CONV_TOTAL) return;
    const float* src; size_t off;
    if (i4 < SZ_X)                { src = x;     off = i4; }
    else if (i4 < 2 * SZ_X)       { src = pos;   off = i4 - SZ_X; }
    else if (i4 < 2 * SZ_X + SZ_QKVW) { src = qkv_w; off = i4 - 2 * SZ_X; }
    else if (i4 < 2 * SZ_X + SZ_QKVW + SZ_PW) { src = pq_w; off = i4 - 2 * SZ_X - SZ_QKVW; }
    else                          { src = pk_w;  off = i4 - 2 * SZ_X - SZ_QKVW - SZ_PW; }
    float4 v = *(const float4*)(src + off);
    ushort4 o;
    o.x = f2bf(v.x); o.y = f2bf(v.y); o.z = f2bf(v.z); o.w = f2bf(v.w);
    *(ushort4*)(dst + i4) = o;
}

// ---------------------------------------------------------------------------
// Kernel 1: fused projection GEMM.
// R21 vs R20 (81.5 us; q2s snapshot spilled to scratch — WRITE 83 MB,
// VGPR=84 < accK 64 + q2s 32; waves_per_eu no-op): EVICT the snapshot from
// registers. At the phase-24 boundary As2 is DEAD (phase-26 data is staged
// into it only inside trip(24)), so Q2k leaves via the standard 4-pass LDS
// epilogue THROUGH As2, computed straight from the live accK. q2s gone ->
// live state back to the clean R18 profile; no scratch. One-time ledger
// over-drain at trip(24)'s first vmcnt(4) (stores are newest) — harmless.
// ---------------------------------------------------------------------------

#define PROJ_STAGE(K0, AS, BS) do {                                          \
    const int k0_ = (K0);                                                    \
    const unsigned short* asrc_; int acol_;                                  \
    if (gg == 3)                    { asrc_ = posb; acol_ = k0_; }           \
    else if (gg == 2 && k0_ >= 768) { asrc_ = posb; acol_ = k0_ - 768; }     \
    else                            { asrc_ = xb;   acol_ = k0_; }           \
    gload_lds16(asrc_ + (size_t)(m0 + r0) * 768 + acol_ + q0 * 8, &AS[base0]);\
    gload_lds16(asrc_ + (size_t)(m0 + r1) * 768 + acol_ + q1 * 8, &AS[base1]);\
    const unsigned short* wsrc_; int wro_, wco_;                             \
    if (gg == 0)      { wsrc_ = qkvw; wro_ = colbase;        wco_ = k0_; }   \
    else if (gg == 1) { wsrc_ = qkvw; wro_ = 1536 + colbase; wco_ = k0_; }   \
    else if (gg == 2) {                                                      \
        if (k0_ < 768) { wsrc_ = qkvw; wro_ = 768 + colbase; wco_ = k0_; }   \
        else           { wsrc_ = pqw;  wro_ = colbase;       wco_ = k0_ - 768; }\
    } else            { wsrc_ = pkw;  wro_ = colbase;        wco_ = k0_; }   \
    gload_lds16(wsrc_ + (size_t)(wro_ + r0) * 768 + wco_ + q0 * 8, &BS[base0]);\
    gload_lds16(wsrc_ + (size_t)(wro_ + r1) * 768 + wco_ + q1 * 8, &BS[base1]);\
} while (0)

#define PROJ_COMPUTE(AS, BS, ACC) do {                                       \
    bf16x8 af[4], bfr[4];                                                    \
    _Pragma("unroll")                                                        \
    for (int mt = 0; mt < 4; ++mt) {                                         \
        const int rr = wm + mt * 16 + col16;                                 \
        af[mt] = *(const bf16x8*)&AS[rr * 32 + ((quad ^ ((rr >> 1) & 3)) * 8)];\
    }                                                                        \
    _Pragma("unroll")                                                        \
    for (int nt = 0; nt < 4; ++nt) {                                         \
        const int rr = wn + nt * 16 + col16;                                 \
        bfr[nt] = *(const bf16x8*)&BS[rr * 32 + ((quad ^ ((rr >> 1) & 3)) * 8)];\
    }                                                                        \
    _Pragma("unroll")                                                        \
    for (int mt = 0; mt < 4; ++mt)                                           \
        _Pragma("unroll")                                                    \
        for (int nt = 0; nt < 4; ++nt)                                       \
            ACC[mt][nt] = MFMA(af[mt], bfr[nt], ACC[mt][nt]);                \
} while (0)

// one 3-phase trip of the ring; staging guards use nk (global K extent)
#define PROJ_TRIP(KT, ACC) do {                                              \
    const int kt_ = (KT);                                                    \
    WAITVM4;                                                                 \
    __syncthreads();                                                         \
    PROJ_STAGE((kt_ + 2) * 32, As2, Bs2);                                    \
    PROJ_COMPUTE(As0, Bs0, ACC);                                             \
    WAITVM4;                                                                 \
    __syncthreads();                                                         \
    if (kt_ + 3 < nk) PROJ_STAGE((kt_ + 3) * 32, As0, Bs0);                  \
    PROJ_COMPUTE(As1, Bs1, ACC);                                             \
    if (kt_ + 3 >= nk) { WAITVM0; } else { WAITVM4; }                        \
    __syncthreads();                                                         \
    if (kt_ + 4 < nk) PROJ_STAGE((kt_ + 4) * 32, As1, Bs1);                  \
    PROJ_COMPUTE(As2, Bs2, ACC);                                             \
} while (0)

// LDS-staged epilogue: 4 passes of 32 rows through LBUF (used [32][128]).
// SRCEXPR is an f32 expression in mt,nt,r; BADDEXPR may use c (col in [0,768));
// DSTEXPR may use b,l,h,dd (dd multiple of 8 -> 16B-aligned store).
#define PROJ_EPI(LBUF, SRCEXPR, BADDEXPR, BMULV, DSTEXPR) do {               \
    _Pragma("unroll")                                                        \
    for (int p = 0; p < 4; ++p) {                                            \
        __syncthreads();                                                     \
        if ((wm >> 6) == (p >> 1)) {                                         \
            _Pragma("unroll")                                                \
            for (int mth = 0; mth < 2; ++mth) {                              \
                const int mt = ((p & 1) << 1) | mth;                         \
                _Pragma("unroll")                                            \
                for (int nt = 0; nt < 4; ++nt) {                             \
                    const int c = colbase + wn + nt * 16 + col16;            \
                    const float badd = (BADDEXPR);                           \
                    const int lrb  = mth * 16 + quad * 4;                    \
                    const int ccol = wn + nt * 16 + col16;                   \
                    _Pragma("unroll")                                        \
                    for (int r = 0; r < 4; ++r)                              \
                        LBUF[(lrb + r) * 128 + ccol] =                       \
                            f2bf(((SRCEXPR) + badd) * (BMULV));              \
                }                                                            \
            }                                                                \
        }                                                                    \
        __syncthreads();                                                     \
        _Pragma("unroll")                                                    \
        for (int j = 0; j < 2; ++j) {                                        \
            const int u = tid + 256 * j;                                     \
            const int rowp = u >> 4;          /* 0..31 */                    \
            const int seg  = u & 15;          /* 8 shorts each */            \
            const int m = m0 + p * 32 + rowp;                                \
            const int b = m >> 10, l = m & 1023;                             \
            const int c = colbase + seg * 8;                                 \
            const int h = c >> 6, dd = c & 63;                               \
            uint4 v = *(const uint4*)&LBUF[rowp * 128 + seg * 8];            \
            *(uint4*)(DSTEXPR) = v;                                          \
        }                                                                    \
    }                                                                        \
} while (0)

__global__ __launch_bounds__(256, 3) void proj_kernel(
    const unsigned short* __restrict__ xb, const unsigned short* __restrict__ posb,
    const unsigned short* __restrict__ qkvw, const unsigned short* __restrict__ pqw,
    const unsigned short* __restrict__ pkw,
    const float* __restrict__ qkv_b, const float* __restrict__ pq_b,
    const float* __restrict__ pk_b,
    unsigned short* __restrict__ Q2, unsigned short* __restrict__ K2,
    unsigned short* __restrict__ Vt, int band)
{
    __shared__ unsigned short As0[128 * 32];
    __shared__ unsigned short As1[128 * 32];
    __shared__ unsigned short As2[128 * 32];
    __shared__ unsigned short Bs0[128 * 32];
    __shared__ unsigned short Bs1[128 * 32];
    __shared__ unsigned short Bs2[128 * 32];

    const int id  = blockIdx.x;
    const int xcd = id & 7;
    const int idx = id >> 3;
    const int t24 = (idx / band + 12) % 24;         // gg2 (dual-K) tiles first
    const int m0 = (xcd * band + idx % band) * 128;
    const int gg = t24 / 6;
    const int colbase = (t24 % 6) * 128;            // column within the group
    const int nk = (gg == 2) ? 48 : 24;             // multiple of 3

    const int tid   = threadIdx.x;
    const int lane  = tid & 63;
    const int w     = tid >> 6;
    const int wm    = (w & 1) * 64;
    const int wn    = (w >> 1) * 64;
    const int quad  = lane >> 4;
    const int col16 = lane & 15;

    const int c0 = w * 64 + lane;
    const int c1 = c0 + 256;
    const int r0 = c0 >> 2, q0 = (c0 & 3) ^ ((c0 >> 3) & 3);
    const int r1 = c1 >> 2, q1 = (c1 & 3) ^ ((c1 >> 3) & 3);
    const int base0 = (w * 64) * 8;
    const int base1 = (w * 64 + 256) * 8;

    f32x4 accK[4][4];
    const f32x4 fzero = {0.f, 0.f, 0.f, 0.f};
#pragma unroll
    for (int mt = 0; mt < 4; ++mt)
#pragma unroll
        for (int nt = 0; nt < 4; ++nt) accK[mt][nt] = fzero;

    // 3-ring prologue: two stages in flight
    PROJ_STAGE(0, As0, Bs0);
    PROJ_STAGE(32, As1, Bs1);

    if (gg == 2) {
        // phases 0-23: x·Wk -> accK
        for (int kt = 0; kt < 24; kt += 3) PROJ_TRIP(kt, accK);

        // Mid-loop Q2k epilogue through As2 (dead until trip(24) stages
        // phase 26). Exact old-g1 arithmetic; coalesced 16B stores; no
        // register snapshot. Pass-0's leading sync fences phase-23 reads.
        PROJ_EPI(As2, accK[mt][nt][r], qkv_b[768 + c], LOG2E / 48.0f,
                 &Q2[((size_t)(b * NHEAD + h) * 1024 + l) * 128 + 64 + dd]);

        // phases 24-47: += pos·Wpq (same acc — R7 g3 accumulation order)
        for (int kt = 24; kt < 48; kt += 3) PROJ_TRIP(kt, accK);

        // K2[0:64] = x·Wk + pos·Wpq + bk + bpq
        PROJ_EPI(As0, accK[mt][nt][r], qkv_b[768 + c] + pq_b[c], 1.0f,
                 &K2[((size_t)(b * NHEAD + h) * 1024 + l) * 128 + dd]);
        return;
    }

    for (int kt = 0; kt < 24; kt += 3) PROJ_TRIP(kt, accK);

    if (gg == 1) {
        // V: 8B uint2 direct path (6/24 tiles only)
#pragma unroll
        for (int mt = 0; mt < 4; ++mt) {
            const int mbase = m0 + wm + mt * 16 + quad * 4;
#pragma unroll
            for (int nt = 0; nt < 4; ++nt) {
                const int c = colbase + wn + nt * 16 + col16;
                const int b = mbase >> 10, l0 = mbase & 1023;
                const int h = c >> 6, dd = c & 63;
                const float bias = qkv_b[1536 + c];
                uint2 pk;
                pk.x = pkbf(accK[mt][nt][0] + bias, accK[mt][nt][1] + bias);
                pk.y = pkbf(accK[mt][nt][2] + bias, accK[mt][nt][3] + bias);
                *(uint2*)&Vt[((size_t)(b * NHEAD + h) * 64 + dd) * 1024 + l0] = pk;
            }
        }
    } else if (gg == 0) {
        PROJ_EPI(As0, accK[mt][nt][r], qkv_b[c], LOG2E,
                 &Q2[((size_t)(b * NHEAD + h) * 1024 + l) * 128 + dd]);
    } else {
        PROJ_EPI(As0, accK[mt][nt][r], pk_b[c], 1.0f,
                 &K2[((size_t)(b * NHEAD + h) * 1024 + l) * 128 + 64 + dd]);
    }
}

// ---------------------------------------------------------------------------
// Kernel 2: flash attention with LAG-1 PV pipelining + counted vmcnt (R16).
// ---------------------------------------------------------------------------

#define ATTN_STG(J0, KS, VS) do {                                            \
    const int j0_ = (J0);                                                    \
    gload_lds16(&K2[q2base + (size_t)(j0_ + kr0) * 128 + kc0 * 8], &KS[kbase0]);\
    gload_lds16(&K2[q2base + (size_t)(j0_ + kr1) * 128 + kc1 * 8], &KS[kbase1]);\
    gload_lds16(&Vt[vtbase + (size_t)vr * 1024 + j0_ + vc * 8],    &VS[vbase]);\
} while (0)

#define ATTN_PV(VS, PSR) do {                                                \
    bf16x8 bp0 = *(const bf16x8*)&PSR[w][col16][quad * 8];                   \
    bf16x8 bp1 = *(const bf16x8*)&PSR[w][16 + col16][quad * 8];              \
    _Pragma("unroll")                                                        \
    for (int c2 = 0; c2 < 4; ++c2) {                                         \
        const int rv = c2 * 16 + col16;                                      \
        bf16x8 av = *(const bf16x8*)&VS[rv * 32 + ((quad ^ ((rv >> 2) & 3)) * 8)];\
        o[0][c2] = MFMA(av, bp0, o[0][c2]);                                  \
        o[1][c2] = MFMA(av, bp1, o[1][c2]);                                  \
    }                                                                        \
} while (0)

#define ATTN_QK(KS, PSW) do {                                                \
    f32x4 st[2][2] = {{fzero, fzero}, {fzero, fzero}};                       \
    _Pragma("unroll")                                                        \
    for (int kk = 0; kk < 4; ++kk) {                                         \
        const int rrj0 = col16, rrj1 = 16 + col16;                           \
        bf16x8 kf0 = *(const bf16x8*)&KS[rrj0 * 128 + (((kk * 4 + quad) ^ (rrj0 & 15)) * 8)];\
        bf16x8 kf1 = *(const bf16x8*)&KS[rrj1 * 128 + (((kk * 4 + quad) ^ (rrj1 & 15)) * 8)];\
        _Pragma("unroll")                                                    \
        for (int qt = 0; qt < 2; ++qt) {                                     \
            st[0][qt] = MFMA(kf0, bq[qt][kk], st[0][qt]);                    \
            st[1][qt] = MFMA(kf1, bq[qt][kk], st[1][qt]);                    \
        }                                                                    \
    }                                                                        \
    _Pragma("unroll")                                                        \
    for (int qt = 0; qt < 2; ++qt) {                                         \
        float p0[4], p1[4], s = 0.f;                                         \
        _Pragma("unroll")                                                    \
        for (int r = 0; r < 4; ++r) {                                        \
            p0[r] = __builtin_amdgcn_exp2f(st[0][qt][r]);                    \
            p1[r] = __builtin_amdgcn_exp2f(st[1][qt][r]);                    \
            s += p0[r] + p1[r];                                              \
        }                                                                    \
        lsum[qt] += s;                                                       \
        uint2 w0, w1;                                                        \
        w0.x = pkbf(p0[0], p0[1]); w0.y = pkbf(p0[2], p0[3]);                \
        w1.x = pkbf(p1[0], p1[1]); w1.y = pkbf(p1[2], p1[3]);                \
        *(uint2*)&PSW[w][qt * 16 + col16][quad * 4]      = w0;               \
        *(uint2*)&PSW[w][qt * 16 + col16][16 + quad * 4] = w1;               \
    }                                                                        \
} while (0)

// phase: DOPV/DOST are compile-time 0/1
#define ATTN_PHASE(J, KQK, KST, VPV, VST, PSW, PSR, DOPV, DOST) do {         \
    WAITVM1;                                                                 \
    __syncthreads();                                                         \
    if (DOST) ATTN_STG(((J) + 1) * 32, KST, VST);                            \
    if (DOPV) ATTN_PV(VPV, PSR);                                             \
    ATTN_QK(KQK, PSW);                                                       \
} while (0)

__global__ __launch_bounds__(256, 3) void attn_kernel(
    const unsigned short* __restrict__ Q2, const unsigned short* __restrict__ K2,
    const unsigned short* __restrict__ Vt, float* __restrict__ out, int b0)
{
    __shared__ unsigned short K2sA[32 * 128];
    __shared__ unsigned short K2sB[32 * 128];
    __shared__ unsigned short VtX[64 * 32];
    __shared__ unsigned short VtY[64 * 32];
    __shared__ unsigned short VtZ[64 * 32];
    __shared__ unsigned short Ps0[4][32][40];
    __shared__ unsigned short Ps1[4][32][40];

    const int bh_l = blockIdx.x;
    const int b = b0 + bh_l / NHEAD, h = bh_l % NHEAD;
    const int tid   = threadIdx.x;
    const int lane  = tid & 63;
    const int w     = tid >> 6;
    const int quad  = lane >> 4;
    const int col16 = lane & 15;
    const int qbase = blockIdx.y * 128 + w * 32;

    const size_t q2base = (size_t)bh_l * 1024 * 128;
    const size_t vtbase = (size_t)bh_l * 64 * 1024;

    const int kL0 = w * 64 + lane, kL1 = kL0 + 256;
    const int kr0 = kL0 >> 4, kc0 = (kL0 & 15) ^ (kr0 & 15);
    const int kr1 = kL1 >> 4, kc1 = (kL1 & 15) ^ (kr1 & 15);
    const int vL  = w * 64 + lane;
    const int vr  = vL >> 2,  vc  = (vL & 3) ^ ((vL >> 4) & 3);
    const int kbase0 = (w * 64) * 8, kbase1 = (w * 64 + 256) * 8;
    const int vbase  = (w * 64) * 8;

    bf16x8 bq[2][4];
#pragma unroll
    for (int qt = 0; qt < 2; ++qt)
#pragma unroll
        for (int kk = 0; kk < 4; ++kk)
            bq[qt][kk] = *(const bf16x8*)&Q2[q2base +
                (size_t)(qbase + qt * 16 + col16) * 128 + kk * 32 + quad * 8];

    f32x4 o[2][4];
    const f32x4 fzero = {0.f, 0.f, 0.f, 0.f};
#pragma unroll
    for (int qt = 0; qt < 2; ++qt)
#pragma unroll
        for (int c2 = 0; c2 < 4; ++c2) o[qt][c2] = fzero;
    float lsum[2] = {0.f, 0.f};

    // prologue: stage 0 -> (K2sA, VtX)
    ATTN_STG(0, K2sA, VtX);

    // phase 0 (pattern J%6==0, no PV): stage 1 -> (K2sB, VtY); QK A -> Ps0
    ATTN_PHASE(0, K2sA, K2sB, VtZ, VtY, Ps0, Ps1, 0, 1);

    // phases 1..30 in 5 trips of 6 (patterns J%6 = 1,2,3,4,5,0)
    for (int j = 1; j < 31; j += 6) {
        ATTN_PHASE(j + 0, K2sB, K2sA, VtX, VtZ, Ps1, Ps0, 1, 1);
        ATTN_PHASE(j + 1, K2sA, K2sB, VtY, VtX, Ps0, Ps1, 1, 1);
        ATTN_PHASE(j + 2, K2sB, K2sA, VtZ, VtY, Ps1, Ps0, 1, 1);
        ATTN_PHASE(j + 3, K2sA, K2sB, VtX, VtZ, Ps0, Ps1, 1, 1);
        ATTN_PHASE(j + 4, K2sB, K2sA, VtY, VtX, Ps1, Ps0, 1, 1);
        ATTN_PHASE(j + 5, K2sA, K2sB, VtZ, VtY, Ps0, Ps1, 1, 1);
    }

    // phase 31 (pattern J%6==1, no stage): PV_30 (VtX, Ps0); QK B -> Ps1
    ATTN_PHASE(31, K2sB, K2sA, VtX, VtZ, Ps1, Ps0, 1, 0);

    // final PV_31: V31 (VtY) was left in flight by phase 31's vmcnt(1)
    // -> drain own DMA, then barrier so all waves' quarters are complete.
    WAITVM0;
    __syncthreads();
    ATTN_PV(VtY, Ps1);

    // ---- final denominator: reduce partials across the 4 sixteens
#pragma unroll
    for (int qt = 0; qt < 2; ++qt) {
        lsum[qt] += __shfl_xor(lsum[qt], 16, 64);
        lsum[qt] += __shfl_xor(lsum[qt], 32, 64);
    }

    // ---- epilogue: o[qt][c2][r] = O^T[d = c2*16+quad*4+r][q]
#pragma unroll
    for (int qt = 0; qt < 2; ++qt) {
        const float inv = 1.0f / lsum[qt];
        const int q = qbase + qt * 16 + col16;
#pragma unroll
        for (int c2 = 0; c2 < 4; ++c2) {
#pragma unroll
            for (int r = 0; r < 4; ++r) {
                const int dd = c2 * 16 + quad * 4 + r;
                out[(((size_t)(b * 1024 + q)) * 12 + h) * 64 + dd] = o[qt][c2][r] * inv;
            }
        }
    }
}

extern "C" void kernel_launch(void* const* d_in, const int* in_sizes, int n_in,
                              void* d_out, int out_size, void* d_ws, size_t ws_size,
                              hipStream_t stream) {
    const float* x     = (const float*)d_in[0];
    const float* pos   = (const float*)d_in[1];
    const float* qkv_w = (const float*)d_in[2];
    const float* qkv_b = (const float*)d_in[3];
    const float* pq_w  = (const float*)d_in[4];
    const float* pq_b  = (const float*)d_in[5];
    const float* pk_w  = (const float*)d_in[6];
    const float* pk_b  = (const float*)d_in[7];
    float* out = (float*)d_out;

    // ws layout (shorts): [xb | posb | qkvw | pqw | pkw | Q2 | K2 | Vt]
    unsigned short* ws   = (unsigned short*)d_ws;
    unsigned short* xb   = ws;
    unsigned short* posb = xb + SZ_X;
    unsigned short* qkvw = posb + SZ_X;
    unsigned short* pqw  = qkvw + SZ_QKVW;
    unsigned short* pkw  = pqw + SZ_PW;
    unsigned short* cbuf = pkw + SZ_PW;              // = ws + CONV_TOTAL

    const size_t conv_bytes = (size_t)CONV_TOTAL * 2;
    const size_t per_batch  = (size_t)NHEAD * 1024 * 128 * 4
                            + (size_t)NHEAD * 64 * 1024 * 2;   // 7,864,320 B
    int cb = BATCH;
    while (cb > 1 && conv_bytes + (size_t)cb * per_batch > ws_size) cb >>= 1;

    unsigned short* Q2 = cbuf;
    unsigned short* K2 = Q2 + (size_t)cb * NHEAD * 1024 * 128;
    unsigned short* Vt = K2 + (size_t)cb * NHEAD * 1024 * 128;

    convert_kernel<<<(CONV_TOTAL / 4 + 255) / 256, 256, 0, stream>>>(
        x, pos, qkv_w, pq_w, pk_w, ws);

    for (int b0 = 0; b0 < BATCH; b0 += cb) {
        proj_kernel<<<dim3(cb * 192), 256, 0, stream>>>(
            xb + (size_t)b0 * 1024 * 768, posb + (size_t)b0 * 1024 * 768,
            qkvw, pqw, pkw, qkv_b, pq_b, pk_b, Q2, K2, Vt, cb);
        attn_kernel<<<dim3(cb * NHEAD, 8), 256, 0, stream>>>(Q2, K2, Vt, out, b0);
    }
}